// Round 8
// baseline (351.351 us; speedup 1.0000x reference)
//
#include <hip/hip_runtime.h>
#include <hip/hip_bf16.h>

// Problem constants (fixed by the reference)
#define N_ROWS 262144
#define IN_DIM 128
#define OUT_DIM 128
#define NTYPES 8
#define ROWS_PER_BLOCK 128  // 2048 blocks = 8 blocks/CU -> 32 waves/CU target
#define GROUP_M 16          // one 16x128 C-tile per group
#define MAX_GROUPS 16       // sum ceil(c_t/16) <= 15 for 128 rows / 8 types
#define EPI_COLS 68         // epilogue half-row stride (64 cols + 4 pad)

typedef short bf16x8 __attribute__((ext_vector_type(8)));   // 8 bf16 in 4 VGPRs
typedef float f32x4 __attribute__((ext_vector_type(4)));

__device__ __forceinline__ unsigned short f2bf_rne(float f) {
    unsigned int u = __float_as_uint(f);
    u += 0x7fff + ((u >> 16) & 1);   // round-nearest-even; inputs finite/normal
    return (unsigned short)(u >> 16);
}

// W [T][IN][OUT] fp32 -> Wb [T][OUT][IN] bf16. 1024 blocks x 128 threads.
__global__ void __launch_bounds__(128) prep_w_kernel(const float* __restrict__ W,
                                                     unsigned short* __restrict__ Wb) {
    const int t = blockIdx.x >> 7;
    const int o = blockIdx.x & 127;
    const int i = threadIdx.x;
    Wb[(t * OUT_DIM + o) * IN_DIM + i] = f2bf_rne(W[(t * IN_DIM + i) * OUT_DIM + o]);
}

__device__ __forceinline__ bf16x8 cvt_8f32_to_bf16(f32x4 f0, f32x4 f1) {
    union { bf16x8 v; __hip_bfloat162 h[4]; } u;
    u.h[0] = __float22bfloat162_rn(make_float2(f0[0], f0[1]));
    u.h[1] = __float22bfloat162_rn(make_float2(f0[2], f0[3]));
    u.h[2] = __float22bfloat162_rn(make_float2(f1[0], f1[1]));
    u.h[3] = __float22bfloat162_rn(make_float2(f1[2], f1[3]));
    return u.v;
}

// r7 post-mortem: VGPR=64 proves the compiler flattened the register prefetch
// pipeline (can't hold araw+anext+acc+frags in 64 regs) -- latency still
// serial, all pipes <5%. r8: take the TLP lever instead. RPB=128 -> 2048
// blocks; LDS shrunk to ~18KB (two-pass epilogue, bias from L2) and VGPR
// pinned <=64 so 8 blocks/CU (32 waves/CU) are resident. r5's failure at this
// occupancy was scattered half-line stores (2.1x traffic); the epilogue now
// stores full 128B lines, so that mode is structurally gone.
__global__ void __launch_bounds__(256, 8) typed_linear_kernel(
        const float* __restrict__ x, const int* __restrict__ xt,
        const unsigned short* __restrict__ Wb, const float* __restrict__ bias,
        float* __restrict__ out) {
    __shared__ float s_out[4][GROUP_M * EPI_COLS];   // 4 waves x 4352 B = 17.4 KB
    __shared__ int s_cnt[NTYPES];
    __shared__ int s_cursor[NTYPES];
    __shared__ unsigned short s_list[ROWS_PER_BLOCK];
    __shared__ unsigned char s_gtype[MAX_GROUPS];
    __shared__ short s_gstart[MAX_GROUPS];
    __shared__ unsigned char s_gcnt[MAX_GROUPS];
    __shared__ int s_ngroups;

    const int tid = threadIdx.x;
    const int row0 = blockIdx.x * ROWS_PER_BLOCK;

    // ---- Phase 1: bucket this block's 128 rows by type ----
    if (tid < NTYPES) s_cnt[tid] = 0;
    __syncthreads();
    int my_t = -1;
    if (tid < ROWS_PER_BLOCK) {
        my_t = xt[row0 + tid];
        atomicAdd(&s_cnt[my_t], 1);
    }
    __syncthreads();
    if (tid == 0) {
        int acc = 0, g = 0;
        for (int i = 0; i < NTYPES; ++i) {
            int c = s_cnt[i];
            s_cursor[i] = acc;
            for (int s = 0; s < c; s += GROUP_M) {
                s_gtype[g] = (unsigned char)i;
                s_gstart[g] = (short)(acc + s);
                s_gcnt[g] = (unsigned char)((c - s) < GROUP_M ? (c - s) : GROUP_M);
                ++g;
            }
            acc += c;
        }
        s_ngroups = g;
    }
    __syncthreads();
    if (tid < ROWS_PER_BLOCK) {
        int pos = atomicAdd(&s_cursor[my_t], 1);
        s_list[pos] = (unsigned short)tid;
    }
    __syncthreads();

    // ---- Phase 2: per-wave MFMA over 16-row groups ----
    const int wave = tid >> 6;
    const int lane = tid & 63;
    const int m = lane & 15;     // A row / B col / C col within 16-tile
    const int q = lane >> 4;     // quad: A k-chunk = q*8.., C rows = q*4..q*4+3
    const int ngroups = s_ngroups;
    float* sow = s_out[wave];

    for (int g = wave; g < ngroups; g += 4) {
        const int t  = s_gtype[g];
        const int gs = s_gstart[g];
        const int gc = s_gcnt[g];

        // A fragments: lane (m,q) reads row m floats [kc*32+q*8, +8).
        // Per load instruction the wave covers 16 rows x contiguous segments.
        const int mm0 = (m < gc) ? m : (gc - 1);   // clamp padded rows (L1 hit)
        const float* ap0 = x + (size_t)(row0 + s_list[gs + mm0]) * IN_DIM + q * 8;
        bf16x8 afrag[4];
        #pragma unroll
        for (int kc = 0; kc < 4; ++kc) {
            const f32x4 f0 = *reinterpret_cast<const f32x4*>(ap0 + kc * 32);
            const f32x4 f1 = *reinterpret_cast<const f32x4*>(ap0 + kc * 32 + 4);
            afrag[kc] = cvt_8f32_to_bf16(f0, f1);
        }

        // Bias for this lane's 8 output columns (L2-resident; issued early so
        // latency hides under the MFMA loop).
        const unsigned short* wt = Wb + t * (IN_DIM * OUT_DIM);
        float bv[8];
        #pragma unroll
        for (int nt = 0; nt < 8; ++nt)
            bv[nt] = bias[t * OUT_DIM + nt * 16 + m];

        // Main loop: 8 output-col tiles, acc persisted; B loads pipeline.
        f32x4 acc[8];
        #pragma unroll
        for (int nt = 0; nt < 8; ++nt) {
            const unsigned short* wcol = wt + (nt * 16 + m) * IN_DIM + q * 8;
            bf16x8 bfr[4];
            #pragma unroll
            for (int kc = 0; kc < 4; ++kc)
                bfr[kc] = *reinterpret_cast<const bf16x8*>(wcol + kc * 32);
            f32x4 a = {0.f, 0.f, 0.f, 0.f};
            #pragma unroll
            for (int kc = 0; kc < 4; ++kc)
                a = __builtin_amdgcn_mfma_f32_16x16x32_bf16(afrag[kc], bfr[kc], a, 0, 0, 0);
            acc[nt] = a;
        }

        // Epilogue: two half-row passes through wave-private LDS (cols
        // [pass*64, +64)). Write banks: (16q + 4r + 16j + m) % 32 -> 2-way max
        // (free). Stores are 256B contiguous = full 128B lines, 1.0x traffic.
        // Same-wave DS ops execute in order -> no barrier between passes.
        #pragma unroll
        for (int pass = 0; pass < 2; ++pass) {
            #pragma unroll
            for (int j = 0; j < 4; ++j) {
                const int nt = pass * 4 + j;
                #pragma unroll
                for (int r = 0; r < 4; ++r)
                    sow[(q * 4 + r) * EPI_COLS + j * 16 + m] = acc[nt][r] + bv[nt];
            }
            const int rsub = lane >> 4;      // row within 4-row slab
            const int c4 = (lane & 15) * 4;  // float col within half-row
            #pragma unroll
            for (int j2 = 0; j2 < 4; ++j2) {
                const int rr = j2 * 4 + rsub;
                if (rr < gc) {
                    const int orow = row0 + s_list[gs + rr];
                    const f32x4 v = *reinterpret_cast<const f32x4*>(&sow[rr * EPI_COLS + c4]);
                    *reinterpret_cast<f32x4*>(&out[(size_t)orow * OUT_DIM + pass * 64 + c4]) = v;
                }
            }
        }
    }
}

extern "C" void kernel_launch(void* const* d_in, const int* in_sizes, int n_in,
                              void* d_out, int out_size, void* d_ws, size_t ws_size,
                              hipStream_t stream) {
    const float* x  = (const float*)d_in[0];
    const int* xt   = (const int*)d_in[1];
    const float* W  = (const float*)d_in[2];
    const float* b  = (const float*)d_in[3];
    float* out      = (float*)d_out;
    unsigned short* Wb = (unsigned short*)d_ws;   // 8*128*128*2 = 256 KiB scratch

    prep_w_kernel<<<NTYPES * OUT_DIM, 128, 0, stream>>>(W, Wb);
    typed_linear_kernel<<<N_ROWS / ROWS_PER_BLOCK, 256, 0, stream>>>(x, xt, Wb, b, out);
}